// Round 1
// 1608.132 us; speedup vs baseline: 1.0755x; 1.0755x over previous
//
#include <hip/hip_runtime.h>
#include <hip/hip_bf16.h>

#define NN      100000
#define NE      1600000
#define RBF     128
#define DIM     64

// ---------- bf16 bit tricks ----------
__device__ __forceinline__ float lo_bf(unsigned int u) {
    union { unsigned int i; float f; } v; v.i = u << 16; return v.f;
}
__device__ __forceinline__ float hi_bf(unsigned int u) {
    union { unsigned int i; float f; } v; v.i = u & 0xffff0000u; return v.f;
}
__device__ __forceinline__ float us_bf(unsigned short u) {
    union { unsigned int i; float f; } v; v.i = ((unsigned int)u) << 16; return v.f;
}

// 64 FMAs into statically-indexed accumulators; w row is wave-uniform -> s_load + v_fmac v,s,v
#define FMA64(accv, rv, wrow) \
    _Pragma("unroll") \
    for (int j = 0; j < 64; ++j) (accv)[j] += (rv) * (wrow)[j];

// ---------- runtime dtype sniffer (+ zero the kept-edge counter) ----------
__global__ void sniff_kernel(const unsigned int* __restrict__ rbf_raw,
                             const unsigned int* __restrict__ mask_raw,
                             int* __restrict__ flags)
{
    const int lane = threadIdx.x & 63;
    int fh = 0, mh = 0;
    for (int i = lane; i < 256; i += 64) {
        const unsigned int u = rbf_raw[i];
        if (((u >> 7) & 0xffu) >= 0x90u) fh = 1;   // low-half bf16 exponent huge -> fp32
        if (mask_raw[i] > 1u) mh = 1;              // int32 bool is only 0/1
    }
    const int fcnt = __popcll(__ballot(fh));
    const int mcnt = __popcll(__ballot(mh));
    if (lane == 0) {
        flags[0] = (fcnt >= 4) ? 1 : 0;
        flags[1] = (mcnt >= 4) ? 1 : 0;
        flags[2] = 0;                              // kept-edge counter
    }
}

// ---------- convert W1/b1/W2/b2 to fp32 into scratch (one layout for both dtypes) ----------
// layout in wf: [0,8192) W1 [128][64], [8192,8256) b1, [8256,12352) W2 [64][64], [12352,12416) b2
__global__ void wconvert_kernel(const void* __restrict__ W1_v,
                                const void* __restrict__ b1_v,
                                const void* __restrict__ W2_v,
                                const void* __restrict__ b2_v,
                                const int* __restrict__ flags,
                                float* __restrict__ wf)
{
    const int f32 = flags[0];
    for (int i = blockIdx.x * blockDim.x + threadIdx.x; i < 12416;
         i += gridDim.x * blockDim.x) {
        float v;
        if (i < 8192) {
            v = f32 ? ((const float*)W1_v)[i] : us_bf(((const unsigned short*)W1_v)[i]);
        } else if (i < 8256) {
            const int j = i - 8192;
            v = f32 ? ((const float*)b1_v)[j] : us_bf(((const unsigned short*)b1_v)[j]);
        } else if (i < 12352) {
            const int j = i - 8256;
            v = f32 ? ((const float*)W2_v)[j] : us_bf(((const unsigned short*)W2_v)[j]);
        } else {
            const int j = i - 12352;
            v = f32 ? ((const float*)b2_v)[j] : us_bf(((const unsigned short*)b2_v)[j]);
        }
        wf[i] = v;
    }
}

// ---------- compact kept-edge ids into a dense list ----------
__global__ void compact_kernel(const void* __restrict__ mask_v,
                               const int* __restrict__ flags,
                               int* __restrict__ kept,
                               int* __restrict__ counter)
{
    const int mask8 = flags[1];
    const int lane = threadIdx.x & 63;
    const int gw = (blockIdx.x * blockDim.x + threadIdx.x) >> 6;
    const int nw = (gridDim.x * blockDim.x) >> 6;
    for (int base = gw * 64; base < NE; base += nw * 64) {
        const int e = base + lane;
        int m = 0;
        if (e < NE)
            m = mask8 ? (int)((const unsigned char*)mask_v)[e]
                      : ((const int*)mask_v)[e];
        const unsigned long long bal = __ballot(m != 0);
        int wbase = 0;
        if (lane == 0) {
            const int cnt = (int)__popcll(bal);
            if (cnt) wbase = atomicAdd(counter, cnt);
        }
        wbase = __shfl(wbase, 0);
        if (m) {
            const int pos = wbase + (int)__popcll(bal & ((1ull << lane) - 1ull));
            kept[pos] = e;
        }
    }
}

// ---------- fused edge kernel: lane = edge, weights via SGPR stream ----------
// Per wave-tile of 64 kept edges:
//   stage1: x[64] per-lane accumulators, W1 rows wave-uniform (s_load operands)
//   softplus in place
//   sp parked in wave-private swizzled LDS tile (enables dynamic j-loop in stage2)
//   stage2: h[64] per-lane, W2 rows wave-uniform
//   h parked in same tile (transpose), scatter with lane = dim so each atomic
//   instruction covers one contiguous 256B accumulator row.
template <bool FP32>
__global__ __launch_bounds__(128, 2)
void edge_kernel(const void* __restrict__ rbf_v,
                 const void* __restrict__ nn_v,
                 const int*  __restrict__ src,
                 const int*  __restrict__ dst,
                 const int*  __restrict__ kept,
                 const float* __restrict__ wf,
                 const int*  __restrict__ flags,
                 float* __restrict__ acc)
{
    if ((flags[0] != 0) != FP32) return;   // uniform: wrong-dtype instance exits
    const int total = flags[2];
    if (total <= 0) return;

    const float* __restrict__ w1f = wf;            // [128][64]
    const float* __restrict__ b1f = wf + 8192;
    const float* __restrict__ w2f = wf + 8256;     // [64][64]
    const float* __restrict__ b2f = wf + 12352;

    const int lane = threadIdx.x & 63;
    const int wib  = threadIdx.x >> 6;
    const int gw   = blockIdx.x * 2 + wib;
    const int nw   = gridDim.x * 2;

    __shared__ float tb[2][64 * 64];               // 32 KB: per-wave 64x64 swizzled tile
    float* __restrict__ tbw = tb[wib];
    // swizzle: (row r, dword j) -> (r<<6) + (((j>>2) ^ (r&15))<<2) + (j&3)

    const int ntiles = (total + 63) >> 6;
    for (int t = gw; t < ntiles; t += nw) {
        const int i0 = t << 6;
        const int valid = min(64, total - i0);
        const int ii = i0 + min(lane, valid - 1);  // clamp tail lanes (dupes never scattered)
        const int eid = kept[ii];
        const int s_l = src[eid];
        const int d_l = dst[eid];

        // ---- stage 1: x[j] = b1[j] + rbf[eid,:] . W1[:,j] ----
        float x[64];
#pragma unroll
        for (int j = 0; j < 64; ++j) x[j] = b1f[j];

        if constexpr (FP32) {
            const float4* __restrict__ rr =
                (const float4*)((const float*)rbf_v + (size_t)eid * RBF);
            for (int k4 = 0; k4 < RBF / 4; ++k4) {
                const float4 r = rr[k4];
                const float* __restrict__ w = w1f + k4 * 256;
                FMA64(x, r.x, w);
                FMA64(x, r.y, w + 64);
                FMA64(x, r.z, w + 128);
                FMA64(x, r.w, w + 192);
            }
        } else {
            const uint4* __restrict__ rr =
                (const uint4*)((const unsigned short*)rbf_v + (size_t)eid * RBF);
            for (int k8 = 0; k8 < RBF / 8; ++k8) {
                const uint4 u = rr[k8];
                const float* __restrict__ w = w1f + k8 * 512;
                const float r0 = lo_bf(u.x), r1 = hi_bf(u.x);
                const float r2 = lo_bf(u.y), r3 = hi_bf(u.y);
                const float r4 = lo_bf(u.z), r5 = hi_bf(u.z);
                const float r6 = lo_bf(u.w), r7 = hi_bf(u.w);
                FMA64(x, r0, w);
                FMA64(x, r1, w + 64);
                FMA64(x, r2, w + 128);
                FMA64(x, r3, w + 192);
                FMA64(x, r4, w + 256);
                FMA64(x, r5, w + 320);
                FMA64(x, r6, w + 384);
                FMA64(x, r7, w + 448);
            }
        }

        // ---- softplus(beta=0.5, threshold=14) in place ----
#pragma unroll
        for (int j = 0; j < 64; ++j) {
            const float bx = 0.5f * x[j];
            const float sp = 2.0f * (fmaxf(bx, 0.0f) + log1pf(__expf(-fabsf(bx))));
            x[j] = (bx > 14.0f) ? x[j] : sp;
        }

        // ---- park sp row in LDS (swizzled); lets stage 2 index sp dynamically ----
#pragma unroll
        for (int c4 = 0; c4 < 16; ++c4) {
            const int sw = (c4 ^ (lane & 15)) << 2;
            float4 v;
            v.x = x[c4 * 4 + 0]; v.y = x[c4 * 4 + 1];
            v.z = x[c4 * 4 + 2]; v.w = x[c4 * 4 + 3];
            *(float4*)&tbw[(lane << 6) + sw] = v;
        }

        // ---- stage 2: h[j2] = b2[j2] + sp[:] . W2[:,j2] ----
        float h[64];
#pragma unroll
        for (int j = 0; j < 64; ++j) h[j] = b2f[j];
        for (int j4 = 0; j4 < 16; ++j4) {
            const int sw = (j4 ^ (lane & 15)) << 2;
            const float4 s4 = *(const float4*)&tbw[(lane << 6) + sw];
            const float* __restrict__ w = w2f + j4 * 256;
            FMA64(h, s4.x, w);
            FMA64(h, s4.y, w + 64);
            FMA64(h, s4.z, w + 128);
            FMA64(h, s4.w, w + 192);
        }

        // ---- park h rows (same swizzle; DS pipe is in-order per wave) ----
#pragma unroll
        for (int c4 = 0; c4 < 16; ++c4) {
            const int sw = (c4 ^ (lane & 15)) << 2;
            float4 v;
            v.x = h[c4 * 4 + 0]; v.y = h[c4 * 4 + 1];
            v.z = h[c4 * 4 + 2]; v.w = h[c4 * 4 + 3];
            *(float4*)&tbw[(lane << 6) + sw] = v;
        }

        // ---- scatter: lane = dim, one contiguous acc row per atomic instruction ----
        for (int e = 0; e < valid; ++e) {
            const int s = __shfl(s_l, e);
            const int d = __shfl(d_l, e);
            const int sw = ((((lane >> 2) ^ (e & 15)) << 2) | (lane & 3));
            const float hv = tbw[(e << 6) + sw];
            float nnv;
            if constexpr (FP32) nnv = ((const float*)nn_v)[(size_t)s * DIM + lane];
            else                nnv = us_bf(((const unsigned short*)nn_v)[(size_t)s * DIM + lane]);
            atomicAdd(&acc[(size_t)d * DIM + lane], nnv * hv);
        }
    }
}

// output dtype follows float-storage flag: fp32 storage -> fp32 out, else bf16
__global__ void finalize_kernel(const float* __restrict__ acc,
                                void* __restrict__ out,
                                const int* __restrict__ flags, int n)
{
    const int i = blockIdx.x * blockDim.x + threadIdx.x;
    if (i < n) {
        const float v = acc[i];
        if (flags[0]) ((float*)out)[i] = v;
        else          ((__hip_bfloat16*)out)[i] = __float2bfloat16(v);
    }
}

extern "C" void kernel_launch(void* const* d_in, const int* in_sizes, int n_in,
                              void* d_out, int out_size, void* d_ws, size_t ws_size,
                              hipStream_t stream)
{
    const void* rbf  = d_in[0];
    const void* nn   = d_in[1];
    const int*  src  = (const int*)d_in[2];
    const int*  dst  = (const int*)d_in[3];
    const void* mask = d_in[4];
    const void* W1   = d_in[5];
    const void* b1   = d_in[6];
    const void* W2   = d_in[7];
    const void* b2   = d_in[8];

    int*   flags = (int*)d_ws;                 // flags[0..1] dtype, flags[2] = kept count
    float* acc   = (float*)d_ws + 64;          // 256B offset; NN*DIM fp32 = 25.6 MB

    // d_out doubles as scratch until finalize overwrites it:
    //   [0, NE*4)            kept-edge id list (worst case 6.4 MB; out_size >= 12.8 MB)
    //   [NE*4, NE*4+48.5KB)  fp32-converted weights
    int*   kept = (int*)d_out;
    float* wf   = (float*)((char*)d_out + (size_t)NE * sizeof(int));

    hipMemsetAsync(acc, 0, (size_t)NN * DIM * sizeof(float), stream);
    sniff_kernel<<<1, 64, 0, stream>>>((const unsigned int*)rbf,
                                       (const unsigned int*)mask, flags);
    wconvert_kernel<<<32, 256, 0, stream>>>(W1, b1, W2, b2, flags, wf);
    compact_kernel<<<512, 256, 0, stream>>>(mask, flags, kept, flags + 2);
    edge_kernel<true ><<<2048, 128, 0, stream>>>(rbf, nn, src, dst, kept, wf, flags, acc);
    edge_kernel<false><<<2048, 128, 0, stream>>>(rbf, nn, src, dst, kept, wf, flags, acc);
    finalize_kernel<<<((NN * DIM) + 255) / 256, 256, 0, stream>>>(
        acc, d_out, flags, NN * DIM);
}